// Round 1
// baseline (4244.967 us; speedup 1.0000x reference)
//
#include <hip/hip_runtime.h>
#include <stdint.h>

typedef uint16_t u16;
typedef short short8 __attribute__((ext_vector_type(8)));
typedef float f32x4 __attribute__((ext_vector_type(4)));

__device__ __forceinline__ u16 f2bf(float f){
  uint32_t u = __float_as_uint(f);
  u += 0x7fff + ((u >> 16) & 1);   // RNE
  return (u16)(u >> 16);
}

__device__ __forceinline__ void mfma16(f32x4& c, short8 a, short8 b){
  asm("v_mfma_f32_16x16x32_bf16 %0, %1, %2, %0" : "+v"(c) : "v"(a), "v"(b));
}

// ---- prep: fp32 -> bf16 cast (vectorized, 8 elems/thread/iter) ----
__global__ void cast_bf16_kernel(const float* __restrict__ src, u16* __restrict__ dst, long n8){
  long i = (long)blockIdx.x * blockDim.x + threadIdx.x;
  long stride = (long)gridDim.x * blockDim.x;
  for (; i < n8; i += stride){
    float4 a = *(const float4*)(src + i*8);
    float4 b = *(const float4*)(src + i*8 + 4);
    u16 r[8] = {f2bf(a.x), f2bf(a.y), f2bf(a.z), f2bf(a.w),
                f2bf(b.x), f2bf(b.y), f2bf(b.z), f2bf(b.w)};
    *(uint4*)(dst + i*8) = *(const uint4*)r;
  }
}

// ---- prep: L = tril(pre) cast to bf16 ; layout (n,u,v) 8x512x512 ----
__global__ void mask_cast_L_kernel(const float* __restrict__ pre, u16* __restrict__ L){
  long i = (long)blockIdx.x * blockDim.x + threadIdx.x;  // chunk of 8 along v
  if (i >= 8L*512*64) return;
  int v0 = (int)(i & 63) * 8;
  int u  = (int)((i >> 6) & 511);
  float4 a = *(const float4*)(pre + i*8);
  float4 b = *(const float4*)(pre + i*8 + 4);
  float vals[8] = {a.x,a.y,a.z,a.w,b.x,b.y,b.z,b.w};
  u16 r[8];
  #pragma unroll
  for (int j=0;j<8;j++) r[j] = f2bf((v0 + j <= u) ? vals[j] : 0.0f);
  *(uint4*)(L + i*8) = *(const uint4*)r;
}

// ---- NT GEMM: C[M,N] = A(MxK,row-major) * B(NxK,row-major)^T ----
// 128x128 tile, BK=64, 4 waves (2x2), each wave 64x64 = 4x4 mfma 16x16x32 frags.
// Batch: z -> (zb = z>>3, zn = z&7); operand offset = zb*sb + zn*sn (elements).
// EPI: 0 = store bf16
//      1 = +bias[row], store bf16
//      2 = v = (col<=row) ? v*scale : 0, store bf16   (row/col local to batch)
//      3 = +bias[col], store fp32
template<int EPI>
__global__ __launch_bounds__(256, 2)
void gemm_nt(const u16* __restrict__ A, const u16* __restrict__ B,
             void* __restrict__ Cv, int K, int lda, int ldb, int ldc,
             long asb, long asn, long bsb, long bsn, long csb, long csn,
             const float* __restrict__ bias, float scale)
{
  __shared__ __align__(16) u16 As[128*64];
  __shared__ __align__(16) u16 Bs[128*64];
  const int t = threadIdx.x;
  const int lane = t & 63;
  const int wave = t >> 6;
  const int wm = wave >> 1, wn = wave & 1;
  const long zb = blockIdx.z >> 3, zn = blockIdx.z & 7;
  A += zb*asb + zn*asn;
  B += zb*bsb + zn*bsn;
  const int row0 = blockIdx.y * 128, col0 = blockIdx.x * 128;
  const int srow = t >> 3;          // 0..31 (+32 per q)
  const int scol = (t & 7) * 8;     // 16B chunk within 64-wide K slab
  const int l15 = lane & 15, l4 = lane >> 4;

  const f32x4 zero = {0.f, 0.f, 0.f, 0.f};
  f32x4 acc[4][4];
  #pragma unroll
  for (int m=0;m<4;m++)
    #pragma unroll
    for (int n=0;n<4;n++) acc[m][n] = zero;

  for (int k0 = 0; k0 < K; k0 += 64){
    uint4 ra[4], rb[4];
    #pragma unroll
    for (int q=0;q<4;q++){
      int r = srow + q*32;
      ra[q] = *(const uint4*)(A + (long)(row0 + r)*lda + k0 + scol);
      rb[q] = *(const uint4*)(B + (long)(col0 + r)*ldb + k0 + scol);
    }
    __syncthreads();                 // previous tile's compute done
    #pragma unroll
    for (int q=0;q<4;q++){
      int r = srow + q*32;
      *(uint4*)&As[r*64 + scol] = ra[q];
      *(uint4*)&Bs[r*64 + scol] = rb[q];
    }
    __syncthreads();
    #pragma unroll
    for (int kc=0;kc<2;kc++){
      short8 af[4], bf[4];
      #pragma unroll
      for (int m=0;m<4;m++)
        af[m] = *(const short8*)&As[(wm*64 + m*16 + l15)*64 + kc*32 + l4*8];
      #pragma unroll
      for (int n=0;n<4;n++)
        bf[n] = *(const short8*)&Bs[(wn*64 + n*16 + l15)*64 + kc*32 + l4*8];
      #pragma unroll
      for (int m=0;m<4;m++)
        #pragma unroll
        for (int n=0;n<4;n++)
          mfma16(acc[m][n], af[m], bf[n]);
    }
  }
  // MFMA (inline asm) -> VALU read hazard cover; compiler can't see through asm
  asm volatile("s_nop 7\n\ts_nop 7\n\ts_nop 7");

  if constexpr (EPI == 3){
    float* C = (float*)Cv;
    #pragma unroll
    for (int m=0;m<4;m++){
      int r0 = row0 + wm*64 + m*16 + l4*4;
      #pragma unroll
      for (int n=0;n<4;n++){
        int c = col0 + wn*64 + n*16 + l15;
        float bc = bias[c];
        #pragma unroll
        for (int g=0; g<4; g++)
          C[(long)(r0+g)*ldc + c] = acc[m][n][g] + bc;
      }
    }
  } else {
    u16* C = (u16*)Cv + zb*csb + zn*csn;
    #pragma unroll
    for (int m=0;m<4;m++){
      int r0 = row0 + wm*64 + m*16 + l4*4;
      #pragma unroll
      for (int n=0;n<4;n++){
        int c = col0 + wn*64 + n*16 + l15;
        #pragma unroll
        for (int g=0;g<4;g++){
          float v = acc[m][n][g];
          int r = r0 + g;
          if constexpr (EPI==1) v += bias[r];
          if constexpr (EPI==2) v = (c <= r) ? v*scale : 0.0f;
          C[(long)r*ldc + c] = f2bf(v);
        }
      }
    }
  }
}

// Workspace layout (bytes):
//   xb   @ 0          : 8192x4096 bf16  (67,108,864)
//   W1b  @ 67108864   : 4096x4096 bf16  (33,554,432)
//   W2b  @ 100663296  : 4096x4096 bf16  (33,554,432)
//   Lb   @ 134217728  : 8x512x512 bf16  ( 4,194,304)
//   Mb   @ 138412032  : 8x512x512 bf16  ( 4,194,304)
//   PtG  @ 142606336  : 4096x8192 bf16  (67,108,864)   PtG[c][r] = P_full[r][c]
//   MPt  @ 209715200  : 128x512x512 bf16 (67,108,864)  MPt[z][j][u] = MP[b,n,u,j]
//   Sb   @ 276824064  : 128x512x512 bf16 (67,108,864)
//   Ob   = MPt (reuse; MPt dead after S-gemm)
// total 343,932,928 bytes

extern "C" void kernel_launch(void* const* d_in, const int* in_sizes, int n_in,
                              void* d_out, int out_size, void* d_ws, size_t ws_size,
                              hipStream_t stream)
{
  (void)in_sizes; (void)n_in; (void)out_size; (void)ws_size;
  const float* x   = (const float*)d_in[0];
  const float* W1  = (const float*)d_in[1];
  const float* b1  = (const float*)d_in[2];
  const float* pre = (const float*)d_in[3];
  const float* W2  = (const float*)d_in[4];
  const float* b2  = (const float*)d_in[5];
  float* out = (float*)d_out;
  char* ws = (char*)d_ws;

  u16* xb  = (u16*)(ws + 0L);
  u16* W1b = (u16*)(ws + 67108864L);
  u16* W2b = (u16*)(ws + 100663296L);
  u16* Lb  = (u16*)(ws + 134217728L);
  u16* Mb  = (u16*)(ws + 138412032L);
  u16* Pt  = (u16*)(ws + 142606336L);
  u16* MPt = (u16*)(ws + 209715200L);
  u16* Sb  = (u16*)(ws + 276824064L);
  u16* Ob  = MPt;  // reuse: MPt consumed by S-gemm before O-gemm writes

  // preps
  cast_bf16_kernel<<<4096,256,0,stream>>>(x,  xb,  4194304L);
  cast_bf16_kernel<<<4096,256,0,stream>>>(W1, W1b, 2097152L);
  cast_bf16_kernel<<<4096,256,0,stream>>>(W2, W2b, 2097152L);
  mask_cast_L_kernel<<<1024,256,0,stream>>>(pre, Lb);

  // M[n] = L[n] ·NT· L[n]          (8 batches, 512^3)
  gemm_nt<0><<<dim3(4,4,8),256,0,stream>>>(Lb, Lb, Mb, 512, 512,512,512,
      0, 262144, 0, 262144, 0, 262144, nullptr, 0.f);

  // PtG = W1b ·NT· xb + b1[row]    (4096 x 8192, K=4096)
  gemm_nt<1><<<dim3(64,32,1),256,0,stream>>>(W1b, xb, Pt, 4096, 4096,4096,8192,
      0,0, 0,0, 0,0, b1, 0.f);

  // MPt[z] = Pt(b,n) ·NT· M[n]     (128 batches, 512^3)
  gemm_nt<0><<<dim3(4,4,128),256,0,stream>>>(Pt, Mb, MPt, 512, 8192,512,512,
      512, 512L*8192, 0, 262144, 8L*262144, 262144, nullptr, 0.f);

  // S[z] = Pt(b,n) ·NT· MPt[z], then *1/sqrt(512) and tril mask
  gemm_nt<2><<<dim3(4,4,128),256,0,stream>>>(Pt, MPt, Sb, 512, 8192,512,512,
      512, 512L*8192, 8L*262144, 262144, 8L*262144, 262144, nullptr, 0.04419417382f);

  // O(b,n) = S[z] ·NT· Pt(b,n)  -> Ob (8192 x 4096, block at [b*512, n*512])
  gemm_nt<0><<<dim3(4,4,128),256,0,stream>>>(Sb, Pt, Ob, 512, 512,8192,4096,
      8L*262144, 262144, 512, 512L*8192, 512L*4096, 512, nullptr, 0.f);

  // Y = Ob ·NT· W2b + b2[col]      (8192 x 4096, K=4096, fp32 out)
  gemm_nt<3><<<dim3(32,64,1),256,0,stream>>>(Ob, W2b, out, 4096, 4096,4096,4096,
      0,0, 0,0, 0,0, b2, 0.f);
}

// Round 2
// 971.609 us; speedup vs baseline: 4.3690x; 4.3690x over previous
//
#include <hip/hip_runtime.h>
#include <stdint.h>

typedef uint16_t u16;
typedef short short8 __attribute__((ext_vector_type(8)));
typedef float f32x4 __attribute__((ext_vector_type(4)));

__device__ __forceinline__ u16 f2bf(float f){
  uint32_t u = __float_as_uint(f);
  u += 0x7fff + ((u >> 16) & 1);   // RNE
  return (u16)(u >> 16);
}

__device__ __forceinline__ void gload_lds16(const u16* g, u16* l){
  __builtin_amdgcn_global_load_lds((const __attribute__((address_space(1))) void*)g,
                                   (__attribute__((address_space(3))) void*)l,
                                   16, 0, 0);
}

// ---- prep: fp32 -> bf16 cast (vectorized, 8 elems/thread/iter) ----
__global__ void cast_bf16_kernel(const float* __restrict__ src, u16* __restrict__ dst, long n8){
  long i = (long)blockIdx.x * blockDim.x + threadIdx.x;
  long stride = (long)gridDim.x * blockDim.x;
  for (; i < n8; i += stride){
    float4 a = *(const float4*)(src + i*8);
    float4 b = *(const float4*)(src + i*8 + 4);
    u16 r[8] = {f2bf(a.x), f2bf(a.y), f2bf(a.z), f2bf(a.w),
                f2bf(b.x), f2bf(b.y), f2bf(b.z), f2bf(b.w)};
    *(uint4*)(dst + i*8) = *(const uint4*)r;
  }
}

// ---- prep: L = tril(pre) cast to bf16 ; layout (n,u,v) 8x512x512 ----
__global__ void mask_cast_L_kernel(const float* __restrict__ pre, u16* __restrict__ L){
  long i = (long)blockIdx.x * blockDim.x + threadIdx.x;  // chunk of 8 along v
  if (i >= 8L*512*64) return;
  int v0 = (int)(i & 63) * 8;
  int u  = (int)((i >> 6) & 511);
  float4 a = *(const float4*)(pre + i*8);
  float4 b = *(const float4*)(pre + i*8 + 4);
  float vals[8] = {a.x,a.y,a.z,a.w,b.x,b.y,b.z,b.w};
  u16 r[8];
  #pragma unroll
  for (int j=0;j<8;j++) r[j] = f2bf((v0 + j <= u) ? vals[j] : 0.0f);
  *(uint4*)(L + i*8) = *(const uint4*)r;
}

// ---- NT GEMM: C[M,N] = A(MxK,row-major) * B(NxK,row-major)^T ----
// m97 structure: 128x128 tile, BK=64, 4 waves (2x2), global_load_lds width-16
// staging into linear LDS, 2 barriers per K-step, 16x16x32 bf16 MFMA builtin.
// Batch: z -> (zb = z>>3, zn = z&7); operand offset = zb*sb + zn*sn (elements).
// EPI: 0 = store bf16
//      1 = +bias[row], store bf16
//      2 = v = (col<=row) ? v*scale : 0, store bf16   (row/col local to batch)
//      3 = +bias[col], store fp32
template<int EPI>
__global__ __launch_bounds__(256, 2)
void gemm_nt(const u16* __restrict__ A, const u16* __restrict__ B,
             void* __restrict__ Cv, int K, int lda, int ldb, int ldc,
             long asb, long asn, long bsb, long bsn, long csb, long csn,
             const float* __restrict__ bias, float scale)
{
  __shared__ __align__(16) u16 As[128*64];
  __shared__ __align__(16) u16 Bs[128*64];
  const int t = threadIdx.x;
  const int lane = t & 63;
  const int wave = t >> 6;
  const int wm = wave >> 1, wn = wave & 1;
  const long zb = blockIdx.z >> 3, zn = blockIdx.z & 7;
  A += zb*asb + zn*asn;
  B += zb*bsb + zn*bsn;
  const int row0 = blockIdx.y * 128, col0 = blockIdx.x * 128;
  const int l15 = lane & 15, l4 = lane >> 4;

  // staging geometry: wave w covers tile rows [w*32, w*32+32), 4 issues of 8 rows;
  // lane l -> row +(l>>3), col elems (l&7)*8  (16B per lane, LDS dest linear)
  const int lrow = lane >> 3;
  const int lcol = (lane & 7) * 8;
  const u16* gA = A + (long)(row0 + wave*32 + lrow)*lda + lcol;
  const u16* gB = B + (long)(col0 + wave*32 + lrow)*ldb + lcol;
  u16* lA = &As[(wave*32)*64];
  u16* lB = &Bs[(wave*32)*64];

  const f32x4 zero = {0.f, 0.f, 0.f, 0.f};
  f32x4 acc[4][4];
  #pragma unroll
  for (int m=0;m<4;m++)
    #pragma unroll
    for (int n=0;n<4;n++) acc[m][n] = zero;

  for (int k0 = 0; k0 < K; k0 += 64){
    #pragma unroll
    for (int q=0;q<4;q++){
      gload_lds16(gA + (long)q*8*lda + k0, lA + q*8*64);
      gload_lds16(gB + (long)q*8*ldb + k0, lB + q*8*64);
    }
    __syncthreads();               // drains vmcnt -> LDS tile ready
    #pragma unroll
    for (int kc=0;kc<2;kc++){
      short8 af[4], bf[4];
      #pragma unroll
      for (int m=0;m<4;m++)
        af[m] = *(const short8*)&As[(wm*64 + m*16 + l15)*64 + kc*32 + l4*8];
      #pragma unroll
      for (int n=0;n<4;n++)
        bf[n] = *(const short8*)&Bs[(wn*64 + n*16 + l15)*64 + kc*32 + l4*8];
      #pragma unroll
      for (int m=0;m<4;m++)
        #pragma unroll
        for (int n=0;n<4;n++)
          acc[m][n] = __builtin_amdgcn_mfma_f32_16x16x32_bf16(af[m], bf[n], acc[m][n], 0, 0, 0);
    }
    __syncthreads();               // all reads done before next-tile overwrite
  }

  if constexpr (EPI == 3){
    float* C = (float*)Cv;
    #pragma unroll
    for (int m=0;m<4;m++){
      int r0 = row0 + wm*64 + m*16 + l4*4;
      #pragma unroll
      for (int n=0;n<4;n++){
        int c = col0 + wn*64 + n*16 + l15;
        float bc = bias[c];
        #pragma unroll
        for (int g=0; g<4; g++)
          C[(long)(r0+g)*ldc + c] = acc[m][n][g] + bc;
      }
    }
  } else {
    u16* C = (u16*)Cv + zb*csb + zn*csn;
    #pragma unroll
    for (int m=0;m<4;m++){
      int r0 = row0 + wm*64 + m*16 + l4*4;
      #pragma unroll
      for (int n=0;n<4;n++){
        int c = col0 + wn*64 + n*16 + l15;
        #pragma unroll
        for (int g=0;g<4;g++){
          float v = acc[m][n][g];
          int r = r0 + g;
          if constexpr (EPI==1) v += bias[r];
          if constexpr (EPI==2) v = (c <= r) ? v*scale : 0.0f;
          C[(long)r*ldc + c] = f2bf(v);
        }
      }
    }
  }
}

// Workspace layout (bytes):
//   xb   @ 0          : 8192x4096 bf16  (67,108,864)
//   W1b  @ 67108864   : 4096x4096 bf16  (33,554,432)
//   W2b  @ 100663296  : 4096x4096 bf16  (33,554,432)
//   Lb   @ 134217728  : 8x512x512 bf16  ( 4,194,304)
//   Mb   @ 138412032  : 8x512x512 bf16  ( 4,194,304)
//   PtG  @ 142606336  : 4096x8192 bf16  (67,108,864)   PtG[c][r] = P_full[r][c]
//   MPt  @ 209715200  : 128x512x512 bf16 (67,108,864)  MPt[z][j][u] = MP[b,n,u,j]
//   Sb   @ 276824064  : 128x512x512 bf16 (67,108,864)
//   Ob   = MPt (reuse; MPt dead after S-gemm)
// total 343,932,928 bytes

extern "C" void kernel_launch(void* const* d_in, const int* in_sizes, int n_in,
                              void* d_out, int out_size, void* d_ws, size_t ws_size,
                              hipStream_t stream)
{
  (void)in_sizes; (void)n_in; (void)out_size; (void)ws_size;
  const float* x   = (const float*)d_in[0];
  const float* W1  = (const float*)d_in[1];
  const float* b1  = (const float*)d_in[2];
  const float* pre = (const float*)d_in[3];
  const float* W2  = (const float*)d_in[4];
  const float* b2  = (const float*)d_in[5];
  float* out = (float*)d_out;
  char* ws = (char*)d_ws;

  u16* xb  = (u16*)(ws + 0L);
  u16* W1b = (u16*)(ws + 67108864L);
  u16* W2b = (u16*)(ws + 100663296L);
  u16* Lb  = (u16*)(ws + 134217728L);
  u16* Mb  = (u16*)(ws + 138412032L);
  u16* Pt  = (u16*)(ws + 142606336L);
  u16* MPt = (u16*)(ws + 209715200L);
  u16* Sb  = (u16*)(ws + 276824064L);
  u16* Ob  = MPt;  // reuse: MPt consumed by S-gemm before O-gemm writes

  // preps
  cast_bf16_kernel<<<4096,256,0,stream>>>(x,  xb,  4194304L);
  cast_bf16_kernel<<<4096,256,0,stream>>>(W1, W1b, 2097152L);
  cast_bf16_kernel<<<4096,256,0,stream>>>(W2, W2b, 2097152L);
  mask_cast_L_kernel<<<1024,256,0,stream>>>(pre, Lb);

  // M[n] = L[n] ·NT· L[n]          (8 batches, 512^3)
  gemm_nt<0><<<dim3(4,4,8),256,0,stream>>>(Lb, Lb, Mb, 512, 512,512,512,
      0, 262144, 0, 262144, 0, 262144, nullptr, 0.f);

  // PtG = W1b ·NT· xb + b1[row]    (4096 x 8192, K=4096)
  gemm_nt<1><<<dim3(64,32,1),256,0,stream>>>(W1b, xb, Pt, 4096, 4096,4096,8192,
      0,0, 0,0, 0,0, b1, 0.f);

  // MPt[z] = Pt(b,n) ·NT· M[n]     (128 batches, 512^3)
  gemm_nt<0><<<dim3(4,4,128),256,0,stream>>>(Pt, Mb, MPt, 512, 8192,512,512,
      512, 512L*8192, 0, 262144, 8L*262144, 262144, nullptr, 0.f);

  // S[z] = Pt(b,n) ·NT· MPt[z], then *1/sqrt(512) and tril mask
  gemm_nt<2><<<dim3(4,4,128),256,0,stream>>>(Pt, MPt, Sb, 512, 8192,512,512,
      512, 512L*8192, 8L*262144, 262144, 8L*262144, 262144, nullptr, 0.04419417382f);

  // O(b,n) = S[z] ·NT· Pt(b,n)  -> Ob (8192 x 4096, block at [b*512, n*512])
  gemm_nt<0><<<dim3(4,4,128),256,0,stream>>>(Sb, Pt, Ob, 512, 512,8192,4096,
      8L*262144, 262144, 512, 512L*8192, 512L*4096, 512, nullptr, 0.f);

  // Y = Ob ·NT· W2b + b2[col]      (8192 x 4096, K=4096, fp32 out)
  gemm_nt<3><<<dim3(32,64,1),256,0,stream>>>(Ob, W2b, out, 4096, 4096,4096,4096,
      0,0, 0,0, 0,0, b2, 0.f);
}

// Round 3
// 762.767 us; speedup vs baseline: 5.5652x; 1.2738x over previous
//
#include <hip/hip_runtime.h>
#include <stdint.h>

typedef uint16_t u16;
typedef short short8 __attribute__((ext_vector_type(8)));
typedef float f32x4 __attribute__((ext_vector_type(4)));

__device__ __forceinline__ u16 f2bf(float f){
  uint32_t u = __float_as_uint(f);
  u += 0x7fff + ((u >> 16) & 1);   // RNE
  return (u16)(u >> 16);
}

__device__ __forceinline__ void gload_lds16(const u16* g, const u16* l){
  __builtin_amdgcn_global_load_lds((const __attribute__((address_space(1))) void*)g,
                                   (__attribute__((address_space(3))) void*)l,
                                   16, 0, 0);
}

// ---- prep: fp32 -> bf16 cast (vectorized, 8 elems/thread/iter) ----
__global__ void cast_bf16_kernel(const float* __restrict__ src, u16* __restrict__ dst, long n8){
  long i = (long)blockIdx.x * blockDim.x + threadIdx.x;
  long stride = (long)gridDim.x * blockDim.x;
  for (; i < n8; i += stride){
    float4 a = *(const float4*)(src + i*8);
    float4 b = *(const float4*)(src + i*8 + 4);
    u16 r[8] = {f2bf(a.x), f2bf(a.y), f2bf(a.z), f2bf(a.w),
                f2bf(b.x), f2bf(b.y), f2bf(b.z), f2bf(b.w)};
    *(uint4*)(dst + i*8) = *(const uint4*)r;
  }
}

// ---- prep: L = tril(pre) cast to bf16 ; layout (n,u,v) 8x512x512 ----
__global__ void mask_cast_L_kernel(const float* __restrict__ pre, u16* __restrict__ L){
  long i = (long)blockIdx.x * blockDim.x + threadIdx.x;  // chunk of 8 along v
  if (i >= 8L*512*64) return;
  int v0 = (int)(i & 63) * 8;
  int u  = (int)((i >> 6) & 511);
  float4 a = *(const float4*)(pre + i*8);
  float4 b = *(const float4*)(pre + i*8 + 4);
  float vals[8] = {a.x,a.y,a.z,a.w,b.x,b.y,b.z,b.w};
  u16 r[8];
  #pragma unroll
  for (int j=0;j<8;j++) r[j] = f2bf((v0 + j <= u) ? vals[j] : 0.0f);
  *(uint4*)(L + i*8) = *(const uint4*)r;
}

// ---- deep-pipelined NT GEMM: C[M,N] = A(MxK,rm) * B(NxK,rm)^T ----
// 256x256 tile, BK=32, 8 waves (2Mx4N), each wave 128x64 = acc[8][4].
// 4 LDS K-tile buffers (32KB each: A 16KB + B 16KB), prefetch 3 ahead,
// counted vmcnt(8) steady state (2 K-tiles in flight across every barrier),
// one barrier per K-tile, 32 MFMA per barrier.
// LDS tiles [256][32] bf16; XOR swizzle byte ^= ((row&3)<<4): applied as
// pre-swizzled GLOBAL source col (linear global_load_lds dest) and the same
// XOR on ds_read addresses (both-sides involution).
// EPI: 0 = store bf16; 1 = +bias[row] bf16; 2 = tril*scale bf16; 3 = +bias[col] fp32.
template<int EPI>
__global__ __launch_bounds__(512, 1)
void gemm_nt2(const u16* __restrict__ A, const u16* __restrict__ B,
              void* __restrict__ Cv, int K, int lda, int ldb, int ldc,
              long asb, long asn, long bsb, long bsn, long csb, long csn,
              const float* __restrict__ bias, float scale)
{
  extern __shared__ __align__(16) char smem[];   // 4 * 32768 = 131072 B
  const int t = threadIdx.x;
  const int lane = t & 63;
  const int wave = t >> 6;          // 0..7
  const int wm = wave >> 2;         // 0..1
  const int wn = wave & 3;          // 0..3
  const long zb = blockIdx.z >> 3, zn = blockIdx.z & 7;
  A += zb*asb + zn*asn;
  B += zb*bsb + zn*bsn;
  const int row0 = blockIdx.y * 256, col0 = blockIdx.x * 256;
  const int l15 = lane & 15, l4 = lane >> 4;

  // staging: thread t covers LDS-linear 16B slot t within an 8KB round
  // (row = t>>2 of 128, col chunk = t&3); source col pre-swizzled by row&3.
  const int srow = t >> 2;                          // 0..127
  const int scol = (((t & 3) ^ (srow & 3)) * 8);    // elements
  const u16* gA = A + (long)(row0 + srow)*lda + scol;
  const u16* gB = B + (long)(col0 + srow)*ldb + scol;
  const long a128 = 128L*(long)lda, b128 = 128L*(long)ldb;
  const int ldsw = wave * 1024;                     // wave-uniform byte base

  // ds_read swizzled col offset (bytes): logical l4*16 XOR (row&3)<<4, row&3==l15&3
  const int csw = (l4 ^ (l15 & 3)) * 16;

  f32x4 acc[8][4];
  #pragma unroll
  for (int m=0;m<8;m++)
    #pragma unroll
    for (int n=0;n<4;n++) acc[m][n] = (f32x4){0.f,0.f,0.f,0.f};

  const int NT = K >> 5;

  auto STAGE = [&](int p){
    char* base = smem + (size_t)((p & 3) * 32768);
    const u16* ga = gA + p*32;
    const u16* gb = gB + p*32;
    gload_lds16(ga,        (const u16*)(base +         ldsw));
    gload_lds16(ga + a128, (const u16*)(base +  8192 + ldsw));
    gload_lds16(gb,        (const u16*)(base + 16384 + ldsw));
    gload_lds16(gb + b128, (const u16*)(base + 24576 + ldsw));
  };

  STAGE(0); STAGE(1); STAGE(2);

  #pragma unroll 1
  for (int tk = 0; tk < NT; ++tk){
    // K-tile tk's 4 loads are exactly the (outstanding-8) oldest in steady state
    if (tk < NT-2)       asm volatile("s_waitcnt vmcnt(8)" ::: "memory");
    else if (tk == NT-2) asm volatile("s_waitcnt vmcnt(4)" ::: "memory");
    else                 asm volatile("s_waitcnt vmcnt(0)" ::: "memory");
    __builtin_amdgcn_s_barrier();
    asm volatile("" ::: "memory");

    const char* bufA = smem + (size_t)((tk & 3) * 32768);
    const char* bufB = bufA + 16384;

    // stage K-tile tk+3 into the buffer whose readers just retired (tk-1's)
    if (tk + 3 < NT) STAGE(tk + 3);

    short8 bfr[4], afr[4];
    #pragma unroll
    for (int n=0;n<4;n++)
      bfr[n] = *(const short8*)(bufB + (wn*64 + n*16 + l15)*64 + csw);
    #pragma unroll
    for (int m=0;m<4;m++)
      afr[m] = *(const short8*)(bufA + (wm*128 + m*16 + l15)*64 + csw);

    __builtin_amdgcn_s_setprio(1);
    #pragma unroll
    for (int m=0;m<4;m++)
      #pragma unroll
      for (int n=0;n<4;n++)
        acc[m][n] = __builtin_amdgcn_mfma_f32_16x16x32_bf16(afr[m], bfr[n], acc[m][n], 0,0,0);
    __builtin_amdgcn_s_setprio(0);

    #pragma unroll
    for (int m=0;m<4;m++)
      afr[m] = *(const short8*)(bufA + (wm*128 + (m+4)*16 + l15)*64 + csw);

    __builtin_amdgcn_s_setprio(1);
    #pragma unroll
    for (int m=0;m<4;m++)
      #pragma unroll
      for (int n=0;n<4;n++)
        acc[m+4][n] = __builtin_amdgcn_mfma_f32_16x16x32_bf16(afr[m], bfr[n], acc[m+4][n], 0,0,0);
    __builtin_amdgcn_s_setprio(0);
  }

  // epilogue: C/D map col=lane&15, row=(lane>>4)*4+g  (HW-verified)
  if constexpr (EPI == 3){
    float* C = (float*)Cv;
    #pragma unroll
    for (int m=0;m<8;m++){
      int r0 = row0 + wm*128 + m*16 + l4*4;
      #pragma unroll
      for (int n=0;n<4;n++){
        int c = col0 + wn*64 + n*16 + l15;
        float bc = bias[c];
        #pragma unroll
        for (int g=0; g<4; g++)
          C[(long)(r0+g)*ldc + c] = acc[m][n][g] + bc;
      }
    }
  } else {
    u16* C = (u16*)Cv + zb*csb + zn*csn;
    #pragma unroll
    for (int m=0;m<8;m++){
      int r0 = row0 + wm*128 + m*16 + l4*4;
      #pragma unroll
      for (int n=0;n<4;n++){
        int c = col0 + wn*64 + n*16 + l15;
        #pragma unroll
        for (int g=0;g<4;g++){
          float v = acc[m][n][g];
          int r = r0 + g;
          if constexpr (EPI==1) v += bias[r];
          if constexpr (EPI==2) v = (c <= r) ? v*scale : 0.0f;
          C[(long)r*ldc + c] = f2bf(v);
        }
      }
    }
  }
}

// Workspace layout (bytes):
//   xb   @ 0          : 8192x4096 bf16
//   W1b  @ 67108864   : 4096x4096 bf16
//   W2b  @ 100663296  : 4096x4096 bf16
//   Lb   @ 134217728  : 8x512x512 bf16
//   Mb   @ 138412032  : 8x512x512 bf16
//   PtG  @ 142606336  : 4096x8192 bf16   PtG[c][r] = P_full[r][c]
//   MPt  @ 209715200  : 128x512x512 bf16 MPt[z][j][u] = MP[b,n,u,j]
//   Sb   @ 276824064  : 128x512x512 bf16
//   Ob   = MPt (reuse; MPt dead after S-gemm)

#define LDSB 131072

extern "C" void kernel_launch(void* const* d_in, const int* in_sizes, int n_in,
                              void* d_out, int out_size, void* d_ws, size_t ws_size,
                              hipStream_t stream)
{
  (void)in_sizes; (void)n_in; (void)out_size; (void)ws_size;
  const float* x   = (const float*)d_in[0];
  const float* W1  = (const float*)d_in[1];
  const float* b1  = (const float*)d_in[2];
  const float* pre = (const float*)d_in[3];
  const float* W2  = (const float*)d_in[4];
  const float* b2  = (const float*)d_in[5];
  float* out = (float*)d_out;
  char* ws = (char*)d_ws;

  u16* xb  = (u16*)(ws + 0L);
  u16* W1b = (u16*)(ws + 67108864L);
  u16* W2b = (u16*)(ws + 100663296L);
  u16* Lb  = (u16*)(ws + 134217728L);
  u16* Mb  = (u16*)(ws + 138412032L);
  u16* Pt  = (u16*)(ws + 142606336L);
  u16* MPt = (u16*)(ws + 209715200L);
  u16* Sb  = (u16*)(ws + 276824064L);
  u16* Ob  = MPt;  // reuse: MPt consumed by S-gemm before O-gemm writes

  hipFuncSetAttribute((const void*)gemm_nt2<0>, hipFuncAttributeMaxDynamicSharedMemorySize, LDSB);
  hipFuncSetAttribute((const void*)gemm_nt2<1>, hipFuncAttributeMaxDynamicSharedMemorySize, LDSB);
  hipFuncSetAttribute((const void*)gemm_nt2<2>, hipFuncAttributeMaxDynamicSharedMemorySize, LDSB);
  hipFuncSetAttribute((const void*)gemm_nt2<3>, hipFuncAttributeMaxDynamicSharedMemorySize, LDSB);

  // preps
  cast_bf16_kernel<<<4096,256,0,stream>>>(x,  xb,  4194304L);
  cast_bf16_kernel<<<4096,256,0,stream>>>(W1, W1b, 2097152L);
  cast_bf16_kernel<<<4096,256,0,stream>>>(W2, W2b, 2097152L);
  mask_cast_L_kernel<<<1024,256,0,stream>>>(pre, Lb);

  // M[n] = L[n] ·NT· L[n]          (8 batches, 512^3)
  gemm_nt2<0><<<dim3(2,2,8),512,LDSB,stream>>>(Lb, Lb, Mb, 512, 512,512,512,
      0, 262144, 0, 262144, 0, 262144, nullptr, 0.f);

  // PtG = W1b ·NT· xb + b1[row]    (4096 x 8192, K=4096)
  gemm_nt2<1><<<dim3(32,16,1),512,LDSB,stream>>>(W1b, xb, Pt, 4096, 4096,4096,8192,
      0,0, 0,0, 0,0, b1, 0.f);

  // MPt[z] = Pt(b,n) ·NT· M[n]     (128 batches, 512^3)
  gemm_nt2<0><<<dim3(2,2,128),512,LDSB,stream>>>(Pt, Mb, MPt, 512, 8192,512,512,
      512, 512L*8192, 0, 262144, 8L*262144, 262144, nullptr, 0.f);

  // S[z] = Pt(b,n) ·NT· MPt[z], then *1/sqrt(512) and tril mask
  gemm_nt2<2><<<dim3(2,2,128),512,LDSB,stream>>>(Pt, MPt, Sb, 512, 8192,512,512,
      512, 512L*8192, 8L*262144, 262144, 8L*262144, 262144, nullptr, 0.04419417382f);

  // O(b,n) = S[z] ·NT· Pt(b,n)  -> Ob (8192 x 4096, block at [b*512, n*512])
  gemm_nt2<0><<<dim3(2,2,128),512,LDSB,stream>>>(Sb, Pt, Ob, 512, 512,8192,4096,
      8L*262144, 262144, 512, 512L*8192, 512L*4096, 512, nullptr, 0.f);

  // Y = Ob ·NT· W2b + b2[col]      (8192 x 4096, K=4096, fp32 out)
  gemm_nt2<3><<<dim3(16,32,1),512,LDSB,stream>>>(Ob, W2b, out, 4096, 4096,4096,4096,
      0,0, 0,0, 0,0, b2, 0.f);
}

// Round 4
// 721.890 us; speedup vs baseline: 5.8803x; 1.0566x over previous
//
#include <hip/hip_runtime.h>
#include <stdint.h>

typedef uint16_t u16;
typedef short short8 __attribute__((ext_vector_type(8)));
typedef float f32x4 __attribute__((ext_vector_type(4)));

__device__ __forceinline__ u16 f2bf(float f){
  uint32_t u = __float_as_uint(f);
  u += 0x7fff + ((u >> 16) & 1);   // RNE
  return (u16)(u >> 16);
}

__device__ __forceinline__ void gload_lds16(const u16* g, const char* l){
  __builtin_amdgcn_global_load_lds((const __attribute__((address_space(1))) void*)g,
                                   (__attribute__((address_space(3))) void*)l,
                                   16, 0, 0);
}

// ---- prep: fp32 -> bf16 cast (vectorized, 8 elems/thread/iter) ----
__global__ void cast_bf16_kernel(const float* __restrict__ src, u16* __restrict__ dst, long n8){
  long i = (long)blockIdx.x * blockDim.x + threadIdx.x;
  long stride = (long)gridDim.x * blockDim.x;
  for (; i < n8; i += stride){
    float4 a = *(const float4*)(src + i*8);
    float4 b = *(const float4*)(src + i*8 + 4);
    u16 r[8] = {f2bf(a.x), f2bf(a.y), f2bf(a.z), f2bf(a.w),
                f2bf(b.x), f2bf(b.y), f2bf(b.z), f2bf(b.w)};
    *(uint4*)(dst + i*8) = *(const uint4*)r;
  }
}

// ---- prep: L = tril(pre) cast to bf16 ; layout (n,u,v) 8x512x512 ----
__global__ void mask_cast_L_kernel(const float* __restrict__ pre, u16* __restrict__ L){
  long i = (long)blockIdx.x * blockDim.x + threadIdx.x;  // chunk of 8 along v
  if (i >= 8L*512*64) return;
  int v0 = (int)(i & 63) * 8;
  int u  = (int)((i >> 6) & 511);
  float4 a = *(const float4*)(pre + i*8);
  float4 b = *(const float4*)(pre + i*8 + 4);
  float vals[8] = {a.x,a.y,a.z,a.w,b.x,b.y,b.z,b.w};
  u16 r[8];
  #pragma unroll
  for (int j=0;j<8;j++) r[j] = f2bf((v0 + j <= u) ? vals[j] : 0.0f);
  *(uint4*)(L + i*8) = *(const uint4*)r;
}

// ---- deep-pipelined NT GEMM: C[M,N] = A(MxK,rm) * B(NxK,rm)^T ----
// 256x256 tile, BK=32, 8 waves (2Mx4N), each wave 128x64 = acc[8][4].
// 4 LDS K-tile buffers (32KB each), prefetch 3 ahead, counted vmcnt(8),
// one barrier per K-tile, 32 MFMA per barrier. K-loop unrolled 4x so buffer
// bases are compile-time. Swizzle g(r)=(r>>1)&3 on 16B chunks: conflict-free
// 8-lane phases (banks (16r+4(l4^g)) mod 32 all distinct). Applied to global
// source (linear gload_lds dest) and ds_read address (both-sides involution).
// EPI: 0 = store bf16; 1 = +bias[row] bf16; 2 = tril*scale bf16; 3 = +bias[col] fp32.
template<int EPI>
__global__ __launch_bounds__(512, 1)
void gemm_nt2(const u16* __restrict__ A, const u16* __restrict__ B,
              void* __restrict__ Cv, int K, int lda, int ldb, int ldc,
              long asb, long asn, long bsb, long bsn, long csb, long csn,
              const float* __restrict__ bias, float scale)
{
  extern __shared__ __align__(16) char smem[];   // 4 * 32768 = 131072 B
  const int t = threadIdx.x;
  const int lane = t & 63;
  const int wave = t >> 6;          // 0..7
  const int wm = wave >> 2;         // 0..1
  const int wn = wave & 3;          // 0..3
  const long zb = blockIdx.z >> 3, zn = blockIdx.z & 7;
  A += zb*asb + zn*asn;
  B += zb*bsb + zn*bsn;
  const int row0 = blockIdx.y * 256, col0 = blockIdx.x * 256;
  const int l15 = lane & 15, l4 = lane >> 4;

  // staging: thread t -> LDS slot t (16B), row = t>>2, chunk pos = t&3;
  // source chunk pre-swizzled: c_g = pos ^ g(row), g(r) = (r>>1)&3
  const int srow = t >> 2;                                // 0..127
  const int scol = (((t & 3) ^ ((srow >> 1) & 3)) * 8);   // elements
  const u16* gA = A + (long)(row0 + srow)*lda + scol;
  const u16* gB = B + (long)(col0 + srow)*ldb + scol;
  const long a128 = 128L*(long)lda, b128 = 128L*(long)ldb;
  const int ldst = t * 16;                                // byte slot

  // ds_read swizzled chunk: pos = l4 ^ g(row), row = (wm*128|m*16)+l15 -> g from l15
  const int csw = (l4 ^ ((l15 >> 1) & 3)) * 16;
  const int raw = (wm*128 + l15)*64 + csw;          // A read base (bytes in buffer)
  const int rbw = 16384 + (wn*64 + l15)*64 + csw;   // B read base

  f32x4 acc[8][4];
  #pragma unroll
  for (int m=0;m<8;m++)
    #pragma unroll
    for (int n=0;n<4;n++) acc[m][n] = (f32x4){0.f,0.f,0.f,0.f};

  const int NT = K >> 5;   // multiples of 16 in practice (K=512/4096)

#define STAGEM(PA, PB, BUF) \
  gload_lds16((PA),        smem + (BUF)*32768 +         ldst); \
  gload_lds16((PA) + a128, smem + (BUF)*32768 +  8192 + ldst); \
  gload_lds16((PB),        smem + (BUF)*32768 + 16384 + ldst); \
  gload_lds16((PB) + b128, smem + (BUF)*32768 + 24576 + ldst);

#define WAITB(VM) \
  asm volatile("s_waitcnt vmcnt(" VM ")" ::: "memory"); \
  __builtin_amdgcn_s_barrier(); \
  asm volatile("" ::: "memory");

#define COMPUTE(BUF) { \
  const char* base = smem + (BUF)*32768; \
  short8 bfr[4], afr[4]; \
  _Pragma("unroll") \
  for (int n=0;n<4;n++) bfr[n] = *(const short8*)(base + rbw + n*1024); \
  _Pragma("unroll") \
  for (int m=0;m<4;m++) afr[m] = *(const short8*)(base + raw + m*1024); \
  __builtin_amdgcn_s_setprio(1); \
  _Pragma("unroll") \
  for (int m=0;m<4;m++) \
    _Pragma("unroll") \
    for (int n=0;n<4;n++) \
      acc[m][n] = __builtin_amdgcn_mfma_f32_16x16x32_bf16(afr[m], bfr[n], acc[m][n], 0,0,0); \
  __builtin_amdgcn_s_setprio(0); \
  _Pragma("unroll") \
  for (int m=0;m<4;m++) afr[m] = *(const short8*)(base + raw + (m+4)*1024); \
  __builtin_amdgcn_s_setprio(1); \
  _Pragma("unroll") \
  for (int m=0;m<4;m++) \
    _Pragma("unroll") \
    for (int n=0;n<4;n++) \
      acc[m+4][n] = __builtin_amdgcn_mfma_f32_16x16x32_bf16(afr[m], bfr[n], acc[m+4][n], 0,0,0); \
  __builtin_amdgcn_s_setprio(0); \
}

  // prologue: 3 K-tiles in flight
  STAGEM(gA,      gB,      0);
  STAGEM(gA + 32, gB + 32, 1);
  STAGEM(gA + 64, gB + 64, 2);

  // main: tiles tk = tb..tb+3 (buffers 0..3), stage tk+3 (buffers 3,0,1,2)
  #pragma unroll 1
  for (int tb = 0; tb < NT - 4; tb += 4){
    const u16* pa = gA + (long)(tb + 3)*32;
    const u16* pb = gB + (long)(tb + 3)*32;
    WAITB("8"); STAGEM(pa,      pb,      3); COMPUTE(0);
    WAITB("8"); STAGEM(pa + 32, pb + 32, 0); COMPUTE(1);
    WAITB("8"); STAGEM(pa + 64, pb + 64, 1); COMPUTE(2);
    WAITB("8"); STAGEM(pa + 96, pb + 96, 2); COMPUTE(3);
  }
  // tail: tk = NT-4..NT-1 (buffers 0..3 since NT%4==0), one last stage
  {
    const u16* pa = gA + (long)(NT - 1)*32;
    const u16* pb = gB + (long)(NT - 1)*32;
    WAITB("8"); STAGEM(pa, pb, 3); COMPUTE(0);
    WAITB("8");                    COMPUTE(1);
    WAITB("4");                    COMPUTE(2);
    WAITB("0");                    COMPUTE(3);
  }
#undef STAGEM
#undef WAITB
#undef COMPUTE

  // epilogue: C/D map col=lane&15, row=(lane>>4)*4+g  (HW-verified)
  if constexpr (EPI == 3){
    float* C = (float*)Cv;
    #pragma unroll
    for (int m=0;m<8;m++){
      int r0 = row0 + wm*128 + m*16 + l4*4;
      #pragma unroll
      for (int n=0;n<4;n++){
        int c = col0 + wn*64 + n*16 + l15;
        float bc = bias[c];
        #pragma unroll
        for (int g=0; g<4; g++)
          C[(long)(r0+g)*ldc + c] = acc[m][n][g] + bc;
      }
    }
  } else {
    u16* C = (u16*)Cv + zb*csb + zn*csn;
    #pragma unroll
    for (int m=0;m<8;m++){
      int r0 = row0 + wm*128 + m*16 + l4*4;
      #pragma unroll
      for (int n=0;n<4;n++){
        int c = col0 + wn*64 + n*16 + l15;
        #pragma unroll
        for (int g=0;g<4;g++){
          float v = acc[m][n][g];
          int r = r0 + g;
          if constexpr (EPI==1) v += bias[r];
          if constexpr (EPI==2) v = (c <= r) ? v*scale : 0.0f;
          C[(long)r*ldc + c] = f2bf(v);
        }
      }
    }
  }
}

// Workspace layout (bytes):
//   xb   @ 0          : 8192x4096 bf16
//   W1b  @ 67108864   : 4096x4096 bf16
//   W2b  @ 100663296  : 4096x4096 bf16
//   Lb   @ 134217728  : 8x512x512 bf16
//   Mb   @ 138412032  : 8x512x512 bf16
//   PtG  @ 142606336  : 4096x8192 bf16   PtG[c][r] = P_full[r][c]
//   MPt  @ 209715200  : 128x512x512 bf16 MPt[z][j][u] = MP[b,n,u,j]
//   Sb   @ 276824064  : 128x512x512 bf16
//   Ob   = MPt (reuse; MPt dead after S-gemm)

#define LDSB 131072

extern "C" void kernel_launch(void* const* d_in, const int* in_sizes, int n_in,
                              void* d_out, int out_size, void* d_ws, size_t ws_size,
                              hipStream_t stream)
{
  (void)in_sizes; (void)n_in; (void)out_size; (void)ws_size;
  const float* x   = (const float*)d_in[0];
  const float* W1  = (const float*)d_in[1];
  const float* b1  = (const float*)d_in[2];
  const float* pre = (const float*)d_in[3];
  const float* W2  = (const float*)d_in[4];
  const float* b2  = (const float*)d_in[5];
  float* out = (float*)d_out;
  char* ws = (char*)d_ws;

  u16* xb  = (u16*)(ws + 0L);
  u16* W1b = (u16*)(ws + 67108864L);
  u16* W2b = (u16*)(ws + 100663296L);
  u16* Lb  = (u16*)(ws + 134217728L);
  u16* Mb  = (u16*)(ws + 138412032L);
  u16* Pt  = (u16*)(ws + 142606336L);
  u16* MPt = (u16*)(ws + 209715200L);
  u16* Sb  = (u16*)(ws + 276824064L);
  u16* Ob  = MPt;  // reuse: MPt consumed by S-gemm before O-gemm writes

  hipFuncSetAttribute((const void*)gemm_nt2<0>, hipFuncAttributeMaxDynamicSharedMemorySize, LDSB);
  hipFuncSetAttribute((const void*)gemm_nt2<1>, hipFuncAttributeMaxDynamicSharedMemorySize, LDSB);
  hipFuncSetAttribute((const void*)gemm_nt2<2>, hipFuncAttributeMaxDynamicSharedMemorySize, LDSB);
  hipFuncSetAttribute((const void*)gemm_nt2<3>, hipFuncAttributeMaxDynamicSharedMemorySize, LDSB);

  // preps
  cast_bf16_kernel<<<4096,256,0,stream>>>(x,  xb,  4194304L);
  cast_bf16_kernel<<<4096,256,0,stream>>>(W1, W1b, 2097152L);
  cast_bf16_kernel<<<4096,256,0,stream>>>(W2, W2b, 2097152L);
  mask_cast_L_kernel<<<1024,256,0,stream>>>(pre, Lb);

  // M[n] = L[n] ·NT· L[n]          (8 batches, 512^3)
  gemm_nt2<0><<<dim3(2,2,8),512,LDSB,stream>>>(Lb, Lb, Mb, 512, 512,512,512,
      0, 262144, 0, 262144, 0, 262144, nullptr, 0.f);

  // PtG = W1b ·NT· xb + b1[row]    (4096 x 8192, K=4096)
  gemm_nt2<1><<<dim3(32,16,1),512,LDSB,stream>>>(W1b, xb, Pt, 4096, 4096,4096,8192,
      0,0, 0,0, 0,0, b1, 0.f);

  // MPt[z] = Pt(b,n) ·NT· M[n]     (128 batches, 512^3)
  gemm_nt2<0><<<dim3(2,2,128),512,LDSB,stream>>>(Pt, Mb, MPt, 512, 8192,512,512,
      512, 512L*8192, 0, 262144, 8L*262144, 262144, nullptr, 0.f);

  // S[z] = Pt(b,n) ·NT· MPt[z], then *1/sqrt(512) and tril mask
  gemm_nt2<2><<<dim3(2,2,128),512,LDSB,stream>>>(Pt, MPt, Sb, 512, 8192,512,512,
      512, 512L*8192, 8L*262144, 262144, 8L*262144, 262144, nullptr, 0.04419417382f);

  // O(b,n) = S[z] ·NT· Pt(b,n)  -> Ob (8192 x 4096, block at [b*512, n*512])
  gemm_nt2<0><<<dim3(2,2,128),512,LDSB,stream>>>(Sb, Pt, Ob, 512, 512,8192,4096,
      8L*262144, 262144, 512, 512L*8192, 512L*4096, 512, nullptr, 0.f);

  // Y = Ob ·NT· W2b + b2[col]      (8192 x 4096, K=4096, fp32 out)
  gemm_nt2<3><<<dim3(16,32,1),512,LDSB,stream>>>(Ob, W2b, out, 4096, 4096,4096,4096,
      0,0, 0,0, 0,0, b2, 0.f);
}